// Round 11
// baseline (150.528 us; speedup 1.0000x reference)
//
#include <hip/hip_runtime.h>

#define NB 4
#define NC 256
#define NN 116380
#define NVEC (NN/4)          // 29095
#define NR 200
#define NL 201
#define NPLANES (NB*NC)      // 1024
#define NFEAT (NB*NR*NC)     // 204800
#define MROI 256             // padded roi rows (rows 208..255 never touched)
#define CHV 64               // voxels per chunk (2 k-steps of 32)
#define NCH 1818             // full chunks: 1818*64 = 116352
#define NTAIL 28             // tail voxels
#define PPB 128              // planes per block
#define AOFFD (PPB*64)       // atlas offset (dwords) within a buffer = 8192
#define BUFD (AOFFD + 64)    // 8256 dwords = 33,024 B
#define NBUF 2               // double buffer -> depth-1 async pipeline

typedef __attribute__((ext_vector_type(8))) short bf16x8;
typedef __attribute__((ext_vector_type(4))) float f32x4;

union BU { uint4 u; bf16x8 v; };

// two f32 -> packed bf16 pair (round-half-up, 2 add + 1 v_perm)
__device__ __forceinline__ unsigned pkbf(float x, float y) {
    unsigned ux = __float_as_uint(x) + 0x8000u;
    unsigned uy = __float_as_uint(y) + 0x8000u;
    return __builtin_amdgcn_perm(uy, ux, 0x07060302u);
}
// packed one-hot pair: lo match -> 0x3F80 (bf16 1.0), hi match -> 0x3F800000
__device__ __forceinline__ unsigned oh2(int l0, int l1, int c) {
    return (l0 == c ? 0x3F80u : 0u) | (l1 == c ? 0x3F800000u : 0u);
}
__device__ __forceinline__ bf16x8 mkA(const int4& la, const int4& lb, int c) {
    union { unsigned u[4]; bf16x8 v; } x;
    x.u[0] = oh2(la.x, la.y, c);
    x.u[1] = oh2(la.z, la.w, c);
    x.u[2] = oh2(lb.x, lb.y, c);
    x.u[3] = oh2(lb.z, lb.w, c);
    return x.v;
}

// ---------------- counts: histogram of atlas labels ----------------
__global__ __launch_bounds__(256) void roi_count(const int* __restrict__ atlas,
                                                 float* __restrict__ counts) {
    __shared__ float h[NL];
    const int tid = threadIdx.x;
    for (int i = tid; i < NL; i += 256) h[i] = 0.0f;
    __syncthreads();
    const int iv = blockIdx.x * 256 + tid;
    if (iv < NVEC) {
        int4 lab = ((const int4*)atlas)[iv];
        atomicAdd(&h[lab.x], 1.0f);
        atomicAdd(&h[lab.y], 1.0f);
        atomicAdd(&h[lab.z], 1.0f);
        atomicAdd(&h[lab.w], 1.0f);
    }
    __syncthreads();
    for (int i = tid; i < NL; i += 256) {
        float v = h[i];
        if (i > 0 && v != 0.0f) atomicAdd(&counts[i - 1], v);
    }
}

// ---------------- main: async pipelined MFMA GEMM, 128-plane blocks ----------
// grid = (64, 8); block = 256 (4 waves). Block C-tile: 256 rois x 128 planes.
// f32 tile [128 rows][64 cols] staged straight to LDS via global_load_lds
// (linear dest; source col pre-swizzled col ^= (row&7)<<2). Double buffer,
// depth-1 counted vmcnt, raw s_barrier. One A-build per k-step feeds 8
// plane-tiles (32 MFMA). Wave 3 computes only roi-tile 12 (rois 192..207).
__global__ __launch_bounds__(256, 2) void roi_accum_w(const float* __restrict__ fm,
                                                      const int* __restrict__ atlas,
                                                      float* __restrict__ partials) {
    __shared__ unsigned lds[NBUF * BUFD];   // 66,048 B
    const int tid  = threadIdx.x;
    const int wave = tid >> 6;
    const int lane = tid & 63;
    const int g    = lane >> 4;
    const int n    = lane & 15;
    const int pb   = blockIdx.y * PPB;
    const int x    = blockIdx.x;
    const int gx   = gridDim.x;

    const int base = NCH / gx, rem = NCH % gx;
    const int c0 = x * base + min(x, rem);
    const int c1 = c0 + base + (x < rem ? 1 : 0);

    f32x4 acc[4][8];
    #pragma unroll
    for (int t = 0; t < 4; ++t)
        #pragma unroll
        for (int p = 0; p < 8; ++p)
            acc[t][p] = (f32x4){0.f, 0.f, 0.f, 0.f};

    const int t0    = wave * 4;
    const int cbase = t0 * 16 + n + 1;
    const int NT    = (wave == 3) ? 1 : 4;    // roi-tiles 13..15 are padding

    // ---- async stage of one chunk into buffer b (9 loads/wave) ----
    auto STAGE = [&](int ch, int b) {
        #pragma unroll
        for (int j = 0; j < 8; ++j) {
            const int row  = (wave * 8 + j) * 4 + (lane >> 4);
            const int colp = (lane & 15) * 4;                  // stored col
            const int col  = colp ^ ((row & 7) << 2);          // source col
            const float* gp = fm + (size_t)(pb + row) * NN + ch * CHV + col;
            unsigned* lp = &lds[b * BUFD + (wave * 8 + j) * 256];
            __builtin_amdgcn_global_load_lds(
                (const __attribute__((address_space(1))) unsigned*)gp,
                (__attribute__((address_space(3))) unsigned*)lp, 16, 0, 0);
        }
        const int* ga = atlas + ch * CHV + lane;               // waves dup (same data)
        __builtin_amdgcn_global_load_lds(
            (const __attribute__((address_space(1))) unsigned*)ga,
            (__attribute__((address_space(3))) unsigned*)&lds[b * BUFD + AOFFD], 4, 0, 0);
    };

    // ---- consume one k-step (32 voxels x 128 planes) from buffer b ----
    auto CONSUME_KS = [&](int b, int ks) {
        const unsigned* ap = &lds[b * BUFD + AOFFD + ks * 32 + 8 * g];
        int4 la = *(const int4*)ap;
        int4 lb = *(const int4*)(ap + 4);
        bf16x8 A0 = mkA(la, lb, cbase);
        bf16x8 A1 = mkA(la, lb, cbase + 16);
        bf16x8 A2 = mkA(la, lb, cbase + 32);
        bf16x8 A3 = mkA(la, lb, cbase + 48);
        #pragma unroll
        for (int p = 0; p < 8; ++p) {
            const int row = p * 16 + n;
            const int xr  = (row & 7) << 2;
            const int cb  = ks * 32 + g * 8;
            f32x4 f0 = *(const f32x4*)&lds[b * BUFD + row * 64 + (cb ^ xr)];
            f32x4 f1 = *(const f32x4*)&lds[b * BUFD + row * 64 + ((cb + 4) ^ xr)];
            BU B;
            B.u = make_uint4(pkbf(f0[0], f0[1]), pkbf(f0[2], f0[3]),
                             pkbf(f1[0], f1[1]), pkbf(f1[2], f1[3]));
            acc[0][p] = __builtin_amdgcn_mfma_f32_16x16x32_bf16(A0, B.v, acc[0][p], 0, 0, 0);
            if (NT > 1) {
                acc[1][p] = __builtin_amdgcn_mfma_f32_16x16x32_bf16(A1, B.v, acc[1][p], 0, 0, 0);
                acc[2][p] = __builtin_amdgcn_mfma_f32_16x16x32_bf16(A2, B.v, acc[2][p], 0, 0, 0);
                acc[3][p] = __builtin_amdgcn_mfma_f32_16x16x32_bf16(A3, B.v, acc[3][p], 0, 0, 0);
            }
        }
    };

    // ---- prologue: fill the pipeline (depth 1) ----
    if (c0 + 0 < c1) STAGE(c0 + 0, 0);
    if (c0 + 1 < c1) STAGE(c0 + 1, 1);

    int b = 0;
    for (int c = c0; c < c1; ++c) {
        const int ahead = min(c1, c + 2) - (c + 1);   // staged chunks beyond c
        if (ahead >= 1) asm volatile("s_waitcnt vmcnt(9)" ::: "memory");
        else            asm volatile("s_waitcnt vmcnt(0)" ::: "memory");
        __builtin_amdgcn_s_barrier();                 // chunk c resident
        __builtin_amdgcn_sched_barrier(0);
        CONSUME_KS(b, 0);
        CONSUME_KS(b, 1);
        __builtin_amdgcn_sched_barrier(0);
        __builtin_amdgcn_s_barrier();                 // all waves done with buf b
        if (c + 2 < c1) STAGE(c + 2, b);              // refill just-freed buffer
        b ^= 1;
    }

    // ---- tail: 28 voxels, block owning the end of the range ----
    if (c1 == NCH && c0 < c1) {
        const int row = tid >> 1;                     // 0..127
        const int hh  = tid & 1;                      // 16-col half of k-step 0
        const int xr  = (row & 7) << 2;
        #pragma unroll
        for (int i = 0; i < 16; ++i) {
            const int cl = hh * 16 + i;               // logical col 0..31
            float v = (cl < NTAIL) ? fm[(size_t)(pb + row) * NN + NCH * CHV + cl] : 0.0f;
            lds[row * 64 + (cl ^ xr)] = __float_as_uint(v);
        }
        if (tid < CHV) {
            int a = (tid < NTAIL) ? atlas[NCH * CHV + tid] : 0;
            lds[AOFFD + tid] = (unsigned)a;
        }
        __syncthreads();
        CONSUME_KS(0, 0);
    }

    // ---- store: partials[x][roi(256, tiles 0..12)][plane(1024)] ----
    // D layout: col = lane&15, row = 4*(lane>>4)+i
    float* pc = partials + (size_t)x * (MROI * NPLANES);
    const int rbase = 4 * g;
    #pragma unroll
    for (int t = 0; t < 4; ++t) {
        if (t < NT) {
            #pragma unroll
            for (int p = 0; p < 8; ++p)
                #pragma unroll
                for (int i = 0; i < 4; ++i)
                    pc[(size_t)((t0 + t) * 16 + rbase + i) * NPLANES + (pb + 16 * p + n)] = acc[t][p][i];
        }
    }
}

// ---------------- finalize: reduce chunks + divide + mask ----------------
__global__ __launch_bounds__(256) void roi_final2(const float* __restrict__ partials,
                                                  const float* __restrict__ counts,
                                                  float* __restrict__ out,
                                                  const int kch) {
    const int j = blockIdx.x * 256 + threadIdx.x;
    if (j < NFEAT) {
        const int c = j & (NC - 1);
        const int r = (j >> 8) % NR;
        const int bb = j / (NR * NC);
        const int plane = bb * NC + c;
        float s = 0.0f;
        for (int ch = 0; ch < kch; ++ch)
            s += partials[((size_t)ch * MROI + r) * NPLANES + plane];
        const float cnt = counts[r];
        out[j] = (cnt > 0.0f) ? s / cnt : 0.0f;
    } else if (j < NFEAT + NB * NR) {
        const int r = (j - NFEAT) % NR;
        out[j] = (counts[r] > 0.0f) ? 1.0f : 0.0f;
    }
}

extern "C" void kernel_launch(void* const* d_in, const int* in_sizes, int n_in,
                              void* d_out, int out_size, void* d_ws, size_t ws_size,
                              hipStream_t stream) {
    const float* fm    = (const float*)d_in[0];
    const int*   atlas = (const int*)d_in[1];
    float*       out   = (float*)d_out;

    float* counts   = (float*)d_ws;     // 256 floats
    float* partials = counts + 256;     // kch * MROI * NPLANES floats

    int kch = 64;                        // 64*8 = 512 blocks = 2/CU exactly
    while (kch > 16 &&
           ws_size < 1024 + (size_t)kch * MROI * NPLANES * sizeof(float))
        kch >>= 1;

    hipMemsetAsync(counts, 0, NR * sizeof(float), stream);

    roi_count<<<(NVEC + 255) / 256, 256, 0, stream>>>(atlas, counts);

    roi_accum_w<<<dim3(kch, NPLANES / PPB), 256, 0, stream>>>(fm, atlas, partials);

    const int total = NFEAT + NB * NR;
    roi_final2<<<(total + 255) / 256, 256, 0, stream>>>(partials, counts, out, kch);
}

// Round 12
// 137.088 us; speedup vs baseline: 1.0980x; 1.0980x over previous
//
#include <hip/hip_runtime.h>

#define NB 4
#define NC 256
#define NN 116380
#define NVEC (NN/4)          // 29095
#define NR 200
#define NL 201
#define NPLANES (NB*NC)      // 1024
#define NFEAT (NB*NR*NC)     // 204800
#define MROI 256             // padded roi rows (rows 208..255 never touched)
#define CHV 96               // voxels per chunk (3 k-steps of 32)
#define NCH 1212             // full chunks: 1212*96 = 116352
#define NTAIL 28             // tail voxels
#define AOFFD (64*CHV)       // atlas offset (dwords) within a buffer = 6144
#define BUFD (AOFFD + 256)   // 6400 dwords = 25,600 B (96 atlas + pad)
#define NBUF 2               // double buffer -> depth-1.5 async pipeline

typedef __attribute__((ext_vector_type(8))) short bf16x8;
typedef __attribute__((ext_vector_type(4))) float f32x4;

union BU { uint4 u; bf16x8 v; };

// two f32 -> packed bf16 pair (round-half-up, 2 add + 1 v_perm)
__device__ __forceinline__ unsigned pkbf(float x, float y) {
    unsigned ux = __float_as_uint(x) + 0x8000u;
    unsigned uy = __float_as_uint(y) + 0x8000u;
    return __builtin_amdgcn_perm(uy, ux, 0x07060302u);
}
// packed one-hot pair: lo match -> 0x3F80 (bf16 1.0), hi match -> 0x3F800000
__device__ __forceinline__ unsigned oh2(int l0, int l1, int c) {
    return (l0 == c ? 0x3F80u : 0u) | (l1 == c ? 0x3F800000u : 0u);
}
__device__ __forceinline__ bf16x8 mkA(const int4& la, const int4& lb, int c) {
    union { unsigned u[4]; bf16x8 v; } x;
    x.u[0] = oh2(la.x, la.y, c);
    x.u[1] = oh2(la.z, la.w, c);
    x.u[2] = oh2(lb.x, lb.y, c);
    x.u[3] = oh2(lb.z, lb.w, c);
    return x.v;
}

// ---------------- counts: histogram of atlas labels ----------------
__global__ __launch_bounds__(256) void roi_count(const int* __restrict__ atlas,
                                                 float* __restrict__ counts) {
    __shared__ float h[NL];
    const int tid = threadIdx.x;
    for (int i = tid; i < NL; i += 256) h[i] = 0.0f;
    __syncthreads();
    const int iv = blockIdx.x * 256 + tid;
    if (iv < NVEC) {
        int4 lab = ((const int4*)atlas)[iv];
        atomicAdd(&h[lab.x], 1.0f);
        atomicAdd(&h[lab.y], 1.0f);
        atomicAdd(&h[lab.z], 1.0f);
        atomicAdd(&h[lab.w], 1.0f);
    }
    __syncthreads();
    for (int i = tid; i < NL; i += 256) {
        float v = h[i];
        if (i > 0 && v != 0.0f) atomicAdd(&counts[i - 1], v);
    }
}

// ---------------- main: async pipelined MFMA GEMM, CHV=96 ----------------
// grid = (KCH, 16); block = 256 (4 waves). Block C-tile: 256 rois x 64 planes.
// f32 tile [64 rows][96 cols] staged straight to LDS via global_load_lds
// (linear dest; source col pre-swizzled col ^= (row&7)<<2). Double buffer,
// counted vmcnt(7) (7 loads/stage), raw s_barrier. bf16 convert at consume.
// Wave 3 computes only roi-tile 12 (rois 192..207); tiles 13-15 are padding.
__global__ __launch_bounds__(256, 3) void roi_accum_96(const float* __restrict__ fm,
                                                       const int* __restrict__ atlas,
                                                       float* __restrict__ partials) {
    __shared__ unsigned lds[NBUF * BUFD];   // 51,200 B -> 3 blocks/CU
    const int tid  = threadIdx.x;
    const int wave = tid >> 6;
    const int lane = tid & 63;
    const int g    = lane >> 4;
    const int n    = lane & 15;
    const int pb   = blockIdx.y * 64;
    const int x    = blockIdx.x;
    const int gx   = gridDim.x;

    const int base = NCH / gx, rem = NCH % gx;
    const int c0 = x * base + min(x, rem);
    const int c1 = c0 + base + (x < rem ? 1 : 0);

    f32x4 acc[4][4];
    #pragma unroll
    for (int t = 0; t < 4; ++t)
        #pragma unroll
        for (int p = 0; p < 4; ++p)
            acc[t][p] = (f32x4){0.f, 0.f, 0.f, 0.f};

    const int t0    = wave * 4;
    const int cbase = t0 * 16 + n + 1;
    const int NT    = (wave == 3) ? 1 : 4;    // roi-tiles 13..15 are padding

    // ---- async stage of one chunk into buffer b (7 loads/wave) ----
    auto STAGE = [&](int ch, int b) {
        #pragma unroll
        for (int j = 0; j < 6; ++j) {
            const int d    = wave * 1536 + j * 256 + lane * 4;   // dword in tile
            const int row  = d / CHV;
            const int col  = d - row * CHV;
            const int scol = col ^ ((row & 7) << 2);             // source swizzle
            const float* gp = fm + (size_t)(pb + row) * NN + ch * CHV + scol;
            unsigned* lp = &lds[b * BUFD + wave * 1536 + j * 256];
            __builtin_amdgcn_global_load_lds(
                (const __attribute__((address_space(1))) unsigned*)gp,
                (__attribute__((address_space(3))) unsigned*)lp, 16, 0, 0);
        }
        if (lane < 24) {                                          // 96 atlas ints
            const int* ga = atlas + ch * CHV + lane * 4;
            __builtin_amdgcn_global_load_lds(
                (const __attribute__((address_space(1))) unsigned*)ga,
                (__attribute__((address_space(3))) unsigned*)&lds[b * BUFD + AOFFD], 16, 0, 0);
        }
    };

    // ---- consume one k-step (32 voxels x 64 planes) from buffer b ----
    auto CONSUME_KS = [&](int b, int ks) {
        const unsigned* ap = &lds[b * BUFD + AOFFD + ks * 32 + 8 * g];
        int4 la = *(const int4*)ap;
        int4 lb = *(const int4*)(ap + 4);
        bf16x8 A0 = mkA(la, lb, cbase), A1, A2, A3;
        if (NT > 1) {
            A1 = mkA(la, lb, cbase + 16);
            A2 = mkA(la, lb, cbase + 32);
            A3 = mkA(la, lb, cbase + 48);
        }
        #pragma unroll
        for (int p = 0; p < 4; ++p) {
            const int row = p * 16 + n;
            const int xr  = (row & 7) << 2;
            const int cb  = ks * 32 + g * 8;
            f32x4 f0 = *(const f32x4*)&lds[b * BUFD + row * CHV + (cb ^ xr)];
            f32x4 f1 = *(const f32x4*)&lds[b * BUFD + row * CHV + ((cb + 4) ^ xr)];
            BU B;
            B.u = make_uint4(pkbf(f0[0], f0[1]), pkbf(f0[2], f0[3]),
                             pkbf(f1[0], f1[1]), pkbf(f1[2], f1[3]));
            acc[0][p] = __builtin_amdgcn_mfma_f32_16x16x32_bf16(A0, B.v, acc[0][p], 0, 0, 0);
            if (NT > 1) {
                acc[1][p] = __builtin_amdgcn_mfma_f32_16x16x32_bf16(A1, B.v, acc[1][p], 0, 0, 0);
                acc[2][p] = __builtin_amdgcn_mfma_f32_16x16x32_bf16(A2, B.v, acc[2][p], 0, 0, 0);
                acc[3][p] = __builtin_amdgcn_mfma_f32_16x16x32_bf16(A3, B.v, acc[3][p], 0, 0, 0);
            }
        }
    };

    // ---- prologue: stage c0 and c0+1 ----
    if (c0 + 0 < c1) STAGE(c0 + 0, 0);
    if (c0 + 1 < c1) STAGE(c0 + 1, 1);

    int b = 0;
    for (int c = c0; c < c1; ++c) {
        if (c + 1 < c1) asm volatile("s_waitcnt vmcnt(7)" ::: "memory");
        else            asm volatile("s_waitcnt vmcnt(0)" ::: "memory");
        __builtin_amdgcn_s_barrier();                 // chunk c resident
        __builtin_amdgcn_sched_barrier(0);
        CONSUME_KS(b, 0);
        CONSUME_KS(b, 1);
        CONSUME_KS(b, 2);
        __builtin_amdgcn_sched_barrier(0);
        __builtin_amdgcn_s_barrier();                 // all waves done with buf b
        if (c + 2 < c1) STAGE(c + 2, b);              // refill just-freed buffer
        b ^= 1;
    }

    // ---- tail: 28 voxels, block owning the end of the range ----
    if (c1 == NCH && c0 < c1) {
        const int row = tid >> 2, scq = tid & 3;
        const int xr  = (row & 7) << 2;
        #pragma unroll
        for (int i = 0; i < 8; ++i) {
            const int cl = scq * 8 + i;               // logical col 0..31
            float v = (cl < NTAIL) ? fm[(size_t)(pb + row) * NN + (size_t)NCH * CHV + cl] : 0.0f;
            lds[row * CHV + (cl ^ xr)] = __float_as_uint(v);
        }
        if (tid < 32) {
            int a = (tid < NTAIL) ? atlas[NCH * CHV + tid] : 0;
            lds[AOFFD + tid] = (unsigned)a;
        }
        __syncthreads();
        CONSUME_KS(0, 0);
    }

    // ---- store: partials[x][roi(256, tiles 0..12)][plane(1024)] ----
    // D layout: col = lane&15, row = 4*(lane>>4)+i
    float* pc = partials + (size_t)x * (MROI * NPLANES);
    const int rbase = 4 * g;
    #pragma unroll
    for (int t = 0; t < 4; ++t) {
        if (t < NT) {
            #pragma unroll
            for (int p = 0; p < 4; ++p)
                #pragma unroll
                for (int i = 0; i < 4; ++i)
                    pc[(size_t)((t0 + t) * 16 + rbase + i) * NPLANES + (pb + 16 * p + n)] = acc[t][p][i];
        }
    }
}

// ---------------- finalize: reduce chunks + divide + mask ----------------
__global__ __launch_bounds__(256) void roi_final2(const float* __restrict__ partials,
                                                  const float* __restrict__ counts,
                                                  float* __restrict__ out,
                                                  const int kch) {
    const int j = blockIdx.x * 256 + threadIdx.x;
    if (j < NFEAT) {
        const int c = j & (NC - 1);
        const int r = (j >> 8) % NR;
        const int bb = j / (NR * NC);
        const int plane = bb * NC + c;
        float s = 0.0f;
        for (int ch = 0; ch < kch; ++ch)
            s += partials[((size_t)ch * MROI + r) * NPLANES + plane];
        const float cnt = counts[r];
        out[j] = (cnt > 0.0f) ? s / cnt : 0.0f;
    } else if (j < NFEAT + NB * NR) {
        const int r = (j - NFEAT) % NR;
        out[j] = (counts[r] > 0.0f) ? 1.0f : 0.0f;
    }
}

extern "C" void kernel_launch(void* const* d_in, const int* in_sizes, int n_in,
                              void* d_out, int out_size, void* d_ws, size_t ws_size,
                              hipStream_t stream) {
    const float* fm    = (const float*)d_in[0];
    const int*   atlas = (const int*)d_in[1];
    float*       out   = (float*)d_out;

    float* counts   = (float*)d_ws;     // 256 floats
    float* partials = counts + 256;     // kch * MROI * NPLANES floats

    int kch = 48;                        // 48*16 = 768 blocks = 3/CU exactly
    while (kch > 12 &&
           ws_size < 1024 + (size_t)kch * MROI * NPLANES * sizeof(float))
        kch >>= 1;

    hipMemsetAsync(counts, 0, NR * sizeof(float), stream);

    roi_count<<<(NVEC + 255) / 256, 256, 0, stream>>>(atlas, counts);

    roi_accum_96<<<dim3(kch, 16), 256, 0, stream>>>(fm, atlas, partials);

    const int total = NFEAT + NB * NR;
    roi_final2<<<(total + 255) / 256, 256, 0, stream>>>(partials, counts, out, kch);
}

// Round 13
// 126.161 us; speedup vs baseline: 1.1931x; 1.0866x over previous
//
#include <hip/hip_runtime.h>

#define NB 4
#define NC 256
#define NN 116380
#define NVEC (NN/4)          // 29095
#define NR 200
#define NL 201
#define NPLANES (NB*NC)      // 1024
#define NFEAT (NB*NR*NC)     // 204800
#define MROI 208             // stored roi rows (13 tiles of 16)
#define CHV 64               // voxels per chunk (2 k-steps of 32)
#define NCH 1818             // full chunks: 1818*64 = 116352
#define NTAIL 28             // tail voxels
#define AOFFD 4096           // atlas offset (dwords) within a buffer
#define BUFD 4160            // 4096 fm f32 + 64 atlas
#define NBUF 3               // triple buffer -> depth-2 async pipeline

typedef __attribute__((ext_vector_type(8))) short bf16x8;
typedef __attribute__((ext_vector_type(4))) float f32x4;

union BU { uint4 u; bf16x8 v; };

// two f32 -> packed bf16 pair (round-half-up, 2 add + 1 v_perm)
__device__ __forceinline__ unsigned pkbf(float x, float y) {
    unsigned ux = __float_as_uint(x) + 0x8000u;
    unsigned uy = __float_as_uint(y) + 0x8000u;
    return __builtin_amdgcn_perm(uy, ux, 0x07060302u);
}
__device__ __forceinline__ unsigned short bf1(float x) {
    return (unsigned short)((__float_as_uint(x) + 0x8000u) >> 16);
}
// packed one-hot pair: lo match -> 0x3F80 (bf16 1.0), hi match -> 0x3F800000
__device__ __forceinline__ unsigned oh2(int l0, int l1, int c) {
    return (l0 == c ? 0x3F80u : 0u) | (l1 == c ? 0x3F800000u : 0u);
}
__device__ __forceinline__ bf16x8 mkA(const int4& la, const int4& lb, int c) {
    union { unsigned u[4]; bf16x8 v; } x;
    x.u[0] = oh2(la.x, la.y, c);
    x.u[1] = oh2(la.z, la.w, c);
    x.u[2] = oh2(lb.x, lb.y, c);
    x.u[3] = oh2(lb.z, lb.w, c);
    return x.v;
}

// ---------------- main: async pipelined MFMA GEMM + fused atlas count ------
// grid = (KCH, 16); block = 256 (4 waves). Block C-tile: 256 rois x 64 planes.
// f32 tile [64 rows][64 cols] staged straight to LDS via global_load_lds
// (linear dest; source col pre-swizzled col ^= (row&7)<<2). Triple buffer,
// depth-2 counted vmcnt, raw s_barrier. bf16 convert at consume.
// Wave 3 computes only roi-tile 12. y==0 blocks also histogram their atlas
// chunk range into counts (integer-valued float adds -> exact/deterministic).
__global__ __launch_bounds__(256, 3) void roi_accum_f(const float* __restrict__ fm,
                                                      const int* __restrict__ atlas,
                                                      unsigned short* __restrict__ partials,
                                                      float* __restrict__ counts) {
    __shared__ unsigned lds[NBUF * BUFD];   // 49,920 B
    const int tid  = threadIdx.x;
    const int wave = tid >> 6;
    const int lane = tid & 63;
    const int g    = lane >> 4;
    const int n    = lane & 15;
    const int pb   = blockIdx.y * 64;
    const int x    = blockIdx.x;
    const int gx   = gridDim.x;

    const int base = NCH / gx, rem = NCH % gx;
    const int c0 = x * base + min(x, rem);
    const int c1 = c0 + base + (x < rem ? 1 : 0);

    f32x4 acc[4][4];
    #pragma unroll
    for (int t = 0; t < 4; ++t)
        #pragma unroll
        for (int p = 0; p < 4; ++p)
            acc[t][p] = (f32x4){0.f, 0.f, 0.f, 0.f};

    const int t0    = wave * 4;
    const int cbase = t0 * 16 + n + 1;
    const int NT    = (wave == 3) ? 1 : 4;    // roi-tiles 13..15 are padding

    // ---- async stage of one chunk into buffer b (5 loads/wave) ----
    auto STAGE = [&](int ch, int b) {
        #pragma unroll
        for (int j = 0; j < 4; ++j) {
            const int row  = wave * 16 + j * 4 + (lane >> 4);
            const int colp = (lane & 15) * 4;                  // stored col
            const int col  = colp ^ ((row & 7) << 2);          // source col
            const float* gp = fm + (size_t)(pb + row) * NN + ch * CHV + col;
            unsigned* lp = &lds[b * BUFD + (wave * 4 + j) * 256];
            __builtin_amdgcn_global_load_lds(
                (const __attribute__((address_space(1))) unsigned*)gp,
                (__attribute__((address_space(3))) unsigned*)lp, 16, 0, 0);
        }
        const int* ga = atlas + ch * CHV + lane;               // waves dup (same data)
        __builtin_amdgcn_global_load_lds(
            (const __attribute__((address_space(1))) unsigned*)ga,
            (__attribute__((address_space(3))) unsigned*)&lds[b * BUFD + AOFFD], 4, 0, 0);
    };

    // ---- consume one k-step (32 voxels) from buffer b ----
    auto CONSUME_KS = [&](int b, int ks) {
        const unsigned* ap = &lds[b * BUFD + AOFFD + ks * 32 + 8 * g];
        int4 la = *(const int4*)ap;
        int4 lb = *(const int4*)(ap + 4);
        BU Bp[4];
        #pragma unroll
        for (int p = 0; p < 4; ++p) {
            const int row = p * 16 + n;
            const int xr  = (row & 7) << 2;
            const int cb  = ks * 32 + g * 8;
            f32x4 f0 = *(const f32x4*)&lds[b * BUFD + row * 64 + (cb ^ xr)];
            f32x4 f1 = *(const f32x4*)&lds[b * BUFD + row * 64 + ((cb + 4) ^ xr)];
            Bp[p].u = make_uint4(pkbf(f0[0], f0[1]), pkbf(f0[2], f0[3]),
                                 pkbf(f1[0], f1[1]), pkbf(f1[2], f1[3]));
        }
        #pragma unroll
        for (int t = 0; t < 4; ++t) {
            if (t < NT) {
                bf16x8 A = mkA(la, lb, cbase + 16 * t);
                acc[t][0] = __builtin_amdgcn_mfma_f32_16x16x32_bf16(A, Bp[0].v, acc[t][0], 0, 0, 0);
                acc[t][1] = __builtin_amdgcn_mfma_f32_16x16x32_bf16(A, Bp[1].v, acc[t][1], 0, 0, 0);
                acc[t][2] = __builtin_amdgcn_mfma_f32_16x16x32_bf16(A, Bp[2].v, acc[t][2], 0, 0, 0);
                acc[t][3] = __builtin_amdgcn_mfma_f32_16x16x32_bf16(A, Bp[3].v, acc[t][3], 0, 0, 0);
            }
        }
    };

    // ---- prologue: fill the pipeline (depth 2) ----
    if (c0 + 0 < c1) STAGE(c0 + 0, 0);
    if (c0 + 1 < c1) STAGE(c0 + 1, 1);
    if (c0 + 2 < c1) STAGE(c0 + 2, 2);

    int b = 0;
    for (int c = c0; c < c1; ++c) {
        const int ahead = min(c1, c + 3) - (c + 1);   // staged chunks beyond c
        if (ahead >= 2)      asm volatile("s_waitcnt vmcnt(10)" ::: "memory");
        else if (ahead == 1) asm volatile("s_waitcnt vmcnt(5)" ::: "memory");
        else                 asm volatile("s_waitcnt vmcnt(0)" ::: "memory");
        __builtin_amdgcn_s_barrier();                 // chunk c resident
        __builtin_amdgcn_sched_barrier(0);
        CONSUME_KS(b, 0);
        CONSUME_KS(b, 1);
        __builtin_amdgcn_sched_barrier(0);
        __builtin_amdgcn_s_barrier();                 // all waves done with buf b
        if (c + 3 < c1) STAGE(c + 3, b);              // refill just-freed buffer
        b = (b == 2) ? 0 : b + 1;
    }

    // ---- tail: 28 voxels, block owning the end of the range ----
    if (c1 == NCH && c0 < c1) {
        const int row = tid >> 2, scq = tid & 3;      // cols scq*8 .. +7
        #pragma unroll
        for (int i = 0; i < 8; ++i) {
            const int cl = scq * 8 + i;               // logical col 0..31
            float v = (cl < NTAIL) ? fm[(size_t)(pb + row) * NN + NCH * CHV + cl] : 0.0f;
            lds[row * 64 + (cl ^ ((row & 7) << 2))] = __float_as_uint(v);
        }
        if (tid < CHV) {
            int a = (tid < NTAIL) ? atlas[NCH * CHV + tid] : 0;
            lds[AOFFD + tid] = (unsigned)a;
        }
        __syncthreads();
        CONSUME_KS(0, 0);
    }

    // ---- store: partials[x][roi(208)][plane(1024)] as bf16 ----
    // D layout: col = lane&15, row = 4*(lane>>4)+i
    unsigned short* pc = partials + (size_t)x * (MROI * NPLANES);
    const int rbase = 4 * g;
    #pragma unroll
    for (int t = 0; t < 4; ++t) {
        if (t < NT) {
            #pragma unroll
            for (int p = 0; p < 4; ++p)
                #pragma unroll
                for (int i = 0; i < 4; ++i)
                    pc[(size_t)((t0 + t) * 16 + rbase + i) * NPLANES + (pb + 16 * p + n)] = bf1(acc[t][p][i]);
        }
    }

    // ---- fused atlas count: y==0 blocks histogram their chunk range ----
    if (blockIdx.y == 0) {
        float* h = (float*)lds;
        __syncthreads();                               // tail consume done
        for (int i = tid; i < NL; i += 256) h[i] = 0.0f;
        __syncthreads();
        const int4* at4b = (const int4*)atlas;
        for (int i = c0 * 16 + tid; i < c1 * 16; i += 256) {
            int4 l = at4b[i];
            atomicAdd(&h[l.x], 1.0f);
            atomicAdd(&h[l.y], 1.0f);
            atomicAdd(&h[l.z], 1.0f);
            atomicAdd(&h[l.w], 1.0f);
        }
        if (c1 == NCH && tid < NTAIL)
            atomicAdd(&h[atlas[NCH * CHV + tid]], 1.0f);
        __syncthreads();
        for (int i = 1 + tid; i < NL; i += 256) {
            float v = h[i];
            if (v != 0.0f) atomicAdd(&counts[i - 1], v);
        }
    }
}

// ---------------- finalize: reduce bf16 partials + divide + mask ----------
__global__ __launch_bounds__(256) void roi_final3(const unsigned short* __restrict__ partials,
                                                  const float* __restrict__ counts,
                                                  float* __restrict__ out,
                                                  const int kch) {
    const int j = blockIdx.x * 256 + threadIdx.x;
    if (j < NFEAT) {
        const int c = j & (NC - 1);
        const int r = (j >> 8) % NR;
        const int bb = j / (NR * NC);
        const int plane = bb * NC + c;
        float s = 0.0f;
        for (int ch = 0; ch < kch; ++ch) {
            unsigned u = partials[((size_t)ch * MROI + r) * NPLANES + plane];
            s += __uint_as_float(u << 16);
        }
        const float cnt = counts[r];
        out[j] = (cnt > 0.0f) ? s / cnt : 0.0f;
    } else if (j < NFEAT + NB * NR) {
        const int r = (j - NFEAT) % NR;
        out[j] = (counts[r] > 0.0f) ? 1.0f : 0.0f;
    }
}

extern "C" void kernel_launch(void* const* d_in, const int* in_sizes, int n_in,
                              void* d_out, int out_size, void* d_ws, size_t ws_size,
                              hipStream_t stream) {
    const float* fm    = (const float*)d_in[0];
    const int*   atlas = (const int*)d_in[1];
    float*       out   = (float*)d_out;

    float*          counts   = (float*)d_ws;              // 256 floats
    unsigned short* partials = (unsigned short*)(counts + 256);

    int kch = 48;                        // 48*16 = 768 blocks = 3/CU exactly
    while (kch > 12 &&
           ws_size < 1024 + (size_t)kch * MROI * NPLANES * sizeof(unsigned short))
        kch >>= 1;

    hipMemsetAsync(counts, 0, NR * sizeof(float), stream);

    roi_accum_f<<<dim3(kch, 16), 256, 0, stream>>>(fm, atlas, partials, counts);

    const int total = NFEAT + NB * NR;
    roi_final3<<<(total + 255) / 256, 256, 0, stream>>>(partials, counts, out, kch);
}

// Round 14
// 124.255 us; speedup vs baseline: 1.2114x; 1.0153x over previous
//
#include <hip/hip_runtime.h>

#define NB 4
#define NC 256
#define NN 116380
#define NVEC (NN/4)          // 29095
#define NR 200
#define NL 201
#define NPLANES (NB*NC)      // 1024
#define NFEAT (NB*NR*NC)     // 204800
#define MROI 208             // stored roi rows (13 tiles of 16)
#define CHV 64               // voxels per chunk (2 k-steps of 32)
#define NCH 1818             // full chunks: 1818*64 = 116352
#define NTAIL 28             // tail voxels
#define AOFFD 4096           // atlas offset (dwords) within a buffer
#define BUFD 4160            // 4096 fm f32 + 64 atlas
#define NBUF 2               // double buffer; 33.3 KB LDS -> 4 blocks/CU

typedef __attribute__((ext_vector_type(8))) short bf16x8;
typedef __attribute__((ext_vector_type(4))) float f32x4;

union BU { uint4 u; bf16x8 v; };

// two f32 -> packed bf16 pair (round-half-up, 2 add + 1 v_perm)
__device__ __forceinline__ unsigned pkbf(float x, float y) {
    unsigned ux = __float_as_uint(x) + 0x8000u;
    unsigned uy = __float_as_uint(y) + 0x8000u;
    return __builtin_amdgcn_perm(uy, ux, 0x07060302u);
}
__device__ __forceinline__ unsigned short bf1(float x) {
    return (unsigned short)((__float_as_uint(x) + 0x8000u) >> 16);
}
// packed one-hot pair: lo match -> 0x3F80 (bf16 1.0), hi match -> 0x3F800000
__device__ __forceinline__ unsigned oh2(int l0, int l1, int c) {
    return (l0 == c ? 0x3F80u : 0u) | (l1 == c ? 0x3F800000u : 0u);
}
__device__ __forceinline__ bf16x8 mkA(const int4& la, const int4& lb, int c) {
    union { unsigned u[4]; bf16x8 v; } x;
    x.u[0] = oh2(la.x, la.y, c);
    x.u[1] = oh2(la.z, la.w, c);
    x.u[2] = oh2(lb.x, lb.y, c);
    x.u[3] = oh2(lb.z, lb.w, c);
    return x.v;
}

// ---------------- main: async pipelined MFMA GEMM + fused atlas count ------
// grid = (KCH, 16); block = 256 (4 waves). Block C-tile: 256 rois x 64 planes.
// f32 tile [64 rows][64 cols] staged straight to LDS via global_load_lds
// (linear dest; source col pre-swizzled col ^= (row&7)<<2). Double buffer,
// counted vmcnt(5), raw s_barrier, 4 blocks/CU (16 waves) for inter-block TLP.
// Wave 3 computes only roi-tile 12. y==0 blocks also histogram their atlas
// chunk range into counts (integer-valued float adds -> exact/deterministic).
__global__ __launch_bounds__(256, 4) void roi_accum_f(const float* __restrict__ fm,
                                                      const int* __restrict__ atlas,
                                                      unsigned short* __restrict__ partials,
                                                      float* __restrict__ counts) {
    __shared__ unsigned lds[NBUF * BUFD];   // 33,280 B
    const int tid  = threadIdx.x;
    const int wave = tid >> 6;
    const int lane = tid & 63;
    const int g    = lane >> 4;
    const int n    = lane & 15;
    const int pb   = blockIdx.y * 64;
    const int x    = blockIdx.x;
    const int gx   = gridDim.x;

    const int base = NCH / gx, rem = NCH % gx;
    const int c0 = x * base + min(x, rem);
    const int c1 = c0 + base + (x < rem ? 1 : 0);

    f32x4 acc[4][4];
    #pragma unroll
    for (int t = 0; t < 4; ++t)
        #pragma unroll
        for (int p = 0; p < 4; ++p)
            acc[t][p] = (f32x4){0.f, 0.f, 0.f, 0.f};

    const int t0    = wave * 4;
    const int cbase = t0 * 16 + n + 1;
    const int NT    = (wave == 3) ? 1 : 4;    // roi-tiles 13..15 are padding

    // ---- async stage of one chunk into buffer b (5 loads/wave) ----
    auto STAGE = [&](int ch, int b) {
        #pragma unroll
        for (int j = 0; j < 4; ++j) {
            const int row  = wave * 16 + j * 4 + (lane >> 4);
            const int colp = (lane & 15) * 4;                  // stored col
            const int col  = colp ^ ((row & 7) << 2);          // source col
            const float* gp = fm + (size_t)(pb + row) * NN + ch * CHV + col;
            unsigned* lp = &lds[b * BUFD + (wave * 4 + j) * 256];
            __builtin_amdgcn_global_load_lds(
                (const __attribute__((address_space(1))) unsigned*)gp,
                (__attribute__((address_space(3))) unsigned*)lp, 16, 0, 0);
        }
        const int* ga = atlas + ch * CHV + lane;               // waves dup (same data)
        __builtin_amdgcn_global_load_lds(
            (const __attribute__((address_space(1))) unsigned*)ga,
            (__attribute__((address_space(3))) unsigned*)&lds[b * BUFD + AOFFD], 4, 0, 0);
    };

    // ---- consume one k-step (32 voxels) from buffer b ----
    auto CONSUME_KS = [&](int b, int ks) {
        const unsigned* ap = &lds[b * BUFD + AOFFD + ks * 32 + 8 * g];
        int4 la = *(const int4*)ap;
        int4 lb = *(const int4*)(ap + 4);
        BU Bp[4];
        #pragma unroll
        for (int p = 0; p < 4; ++p) {
            const int row = p * 16 + n;
            const int xr  = (row & 7) << 2;
            const int cb  = ks * 32 + g * 8;
            f32x4 f0 = *(const f32x4*)&lds[b * BUFD + row * 64 + (cb ^ xr)];
            f32x4 f1 = *(const f32x4*)&lds[b * BUFD + row * 64 + ((cb + 4) ^ xr)];
            Bp[p].u = make_uint4(pkbf(f0[0], f0[1]), pkbf(f0[2], f0[3]),
                                 pkbf(f1[0], f1[1]), pkbf(f1[2], f1[3]));
        }
        #pragma unroll
        for (int t = 0; t < 4; ++t) {
            if (t < NT) {
                bf16x8 A = mkA(la, lb, cbase + 16 * t);
                acc[t][0] = __builtin_amdgcn_mfma_f32_16x16x32_bf16(A, Bp[0].v, acc[t][0], 0, 0, 0);
                acc[t][1] = __builtin_amdgcn_mfma_f32_16x16x32_bf16(A, Bp[1].v, acc[t][1], 0, 0, 0);
                acc[t][2] = __builtin_amdgcn_mfma_f32_16x16x32_bf16(A, Bp[2].v, acc[t][2], 0, 0, 0);
                acc[t][3] = __builtin_amdgcn_mfma_f32_16x16x32_bf16(A, Bp[3].v, acc[t][3], 0, 0, 0);
            }
        }
    };

    // ---- prologue: stage c0 and c0+1 ----
    if (c0 + 0 < c1) STAGE(c0 + 0, 0);
    if (c0 + 1 < c1) STAGE(c0 + 1, 1);

    int b = 0;
    for (int c = c0; c < c1; ++c) {
        if (c + 1 < c1) asm volatile("s_waitcnt vmcnt(5)" ::: "memory");
        else            asm volatile("s_waitcnt vmcnt(0)" ::: "memory");
        __builtin_amdgcn_s_barrier();                 // chunk c resident
        __builtin_amdgcn_sched_barrier(0);
        CONSUME_KS(b, 0);
        CONSUME_KS(b, 1);
        __builtin_amdgcn_sched_barrier(0);
        __builtin_amdgcn_s_barrier();                 // all waves done with buf b
        if (c + 2 < c1) STAGE(c + 2, b);              // refill just-freed buffer
        b ^= 1;
    }

    // ---- tail: 28 voxels, block owning the end of the range ----
    if (c1 == NCH && c0 < c1) {
        const int row = tid >> 2, scq = tid & 3;      // cols scq*8 .. +7
        #pragma unroll
        for (int i = 0; i < 8; ++i) {
            const int cl = scq * 8 + i;               // logical col 0..31
            float v = (cl < NTAIL) ? fm[(size_t)(pb + row) * NN + NCH * CHV + cl] : 0.0f;
            lds[row * 64 + (cl ^ ((row & 7) << 2))] = __float_as_uint(v);
        }
        if (tid < CHV) {
            int a = (tid < NTAIL) ? atlas[NCH * CHV + tid] : 0;
            lds[AOFFD + tid] = (unsigned)a;
        }
        __syncthreads();
        CONSUME_KS(0, 0);
    }

    // ---- store: partials[x][roi(208)][plane(1024)] as bf16 ----
    // D layout: col = lane&15, row = 4*(lane>>4)+i
    unsigned short* pc = partials + (size_t)x * (MROI * NPLANES);
    const int rbase = 4 * g;
    #pragma unroll
    for (int t = 0; t < 4; ++t) {
        if (t < NT) {
            #pragma unroll
            for (int p = 0; p < 4; ++p)
                #pragma unroll
                for (int i = 0; i < 4; ++i)
                    pc[(size_t)((t0 + t) * 16 + rbase + i) * NPLANES + (pb + 16 * p + n)] = bf1(acc[t][p][i]);
        }
    }

    // ---- fused atlas count: y==0 blocks histogram their chunk range ----
    if (blockIdx.y == 0) {
        float* h = (float*)lds;
        __syncthreads();                               // tail consume done
        for (int i = tid; i < NL; i += 256) h[i] = 0.0f;
        __syncthreads();
        const int4* at4b = (const int4*)atlas;
        for (int i = c0 * 16 + tid; i < c1 * 16; i += 256) {
            int4 l = at4b[i];
            atomicAdd(&h[l.x], 1.0f);
            atomicAdd(&h[l.y], 1.0f);
            atomicAdd(&h[l.z], 1.0f);
            atomicAdd(&h[l.w], 1.0f);
        }
        if (c1 == NCH && tid < NTAIL)
            atomicAdd(&h[atlas[NCH * CHV + tid]], 1.0f);
        __syncthreads();
        for (int i = 1 + tid; i < NL; i += 256) {
            float v = h[i];
            if (v != 0.0f) atomicAdd(&counts[i - 1], v);
        }
    }
}

// ---------------- finalize: reduce bf16 partials + divide + mask ----------
__global__ __launch_bounds__(256) void roi_final3(const unsigned short* __restrict__ partials,
                                                  const float* __restrict__ counts,
                                                  float* __restrict__ out,
                                                  const int kch) {
    const int j = blockIdx.x * 256 + threadIdx.x;
    if (j < NFEAT) {
        const int c = j & (NC - 1);
        const int r = (j >> 8) % NR;
        const int bb = j / (NR * NC);
        const int plane = bb * NC + c;
        float s = 0.0f;
        for (int ch = 0; ch < kch; ++ch) {
            unsigned u = partials[((size_t)ch * MROI + r) * NPLANES + plane];
            s += __uint_as_float(u << 16);
        }
        const float cnt = counts[r];
        out[j] = (cnt > 0.0f) ? s / cnt : 0.0f;
    } else if (j < NFEAT + NB * NR) {
        const int r = (j - NFEAT) % NR;
        out[j] = (counts[r] > 0.0f) ? 1.0f : 0.0f;
    }
}

extern "C" void kernel_launch(void* const* d_in, const int* in_sizes, int n_in,
                              void* d_out, int out_size, void* d_ws, size_t ws_size,
                              hipStream_t stream) {
    const float* fm    = (const float*)d_in[0];
    const int*   atlas = (const int*)d_in[1];
    float*       out   = (float*)d_out;

    float*          counts   = (float*)d_ws;              // 256 floats
    unsigned short* partials = (unsigned short*)(counts + 256);

    int kch = 64;                        // 64*16 = 1024 blocks = 4/CU exactly
    while (kch > 16 &&
           ws_size < 1024 + (size_t)kch * MROI * NPLANES * sizeof(unsigned short))
        kch >>= 1;

    hipMemsetAsync(counts, 0, NR * sizeof(float), stream);

    roi_accum_f<<<dim3(kch, 16), 256, 0, stream>>>(fm, atlas, partials, counts);

    const int total = NFEAT + NB * NR;
    roi_final3<<<(total + 255) / 256, 256, 0, stream>>>(partials, counts, out, kch);
}